// Round 4
// baseline (123.597 us; speedup 1.0000x reference)
//
#include <hip/hip_runtime.h>
#include <hip/hip_bf16.h>

#define B_N 32
#define T_N 512
#define D_N 512
#define H_N 512
#define M_N (B_N * T_N)   // 16384

typedef __attribute__((ext_vector_type(8))) short bf16x8;
typedef __attribute__((ext_vector_type(4))) float f32x4;

__device__ __forceinline__ unsigned short f2bf(float f) {
  unsigned u = __float_as_uint(f);
  u += 0x7FFFu + ((u >> 16) & 1u);   // RTNE
  return (unsigned short)(u >> 16);
}
__device__ __forceinline__ float bf2f(unsigned short h) {
  return __uint_as_float(((unsigned)h) << 16);
}

#define GLOAD16(g, l) __builtin_amdgcn_global_load_lds( \
    (const __attribute__((address_space(1))) void*)(g), \
    (__attribute__((address_space(3))) void*)(l), 16, 0, 0)

// ---------------------------------------------------------------------------
// prep: blocks [0,768) transpose+convert the 3 weight matrices (W[k][n] ->
// Wt[id][n][k] bf16); blocks [768, 2816) convert x f32 -> bf16.
// ---------------------------------------------------------------------------
__global__ void prep_kernel(const float* __restrict__ x,
                            const float* __restrict__ W0,
                            const float* __restrict__ W1,
                            const float* __restrict__ W2,
                            unsigned short* __restrict__ xb,
                            unsigned short* __restrict__ Wt) {
  int blk = blockIdx.x;
  int tid = threadIdx.x;
  if (blk < 768) {
    __shared__ float tile[32][33];
    int id = blk >> 8;
    int t = blk & 255;
    int kr = (t >> 4) << 5;
    int nc = (t & 15) << 5;
    const float* W = (id == 0) ? W0 : (id == 1) ? W1 : W2;
    unsigned short* Wo = Wt + (size_t)id * (D_N * H_N);
    int tx = tid & 31, ty0 = tid >> 5;
    for (int ty = ty0; ty < 32; ty += 8)
      tile[ty][tx] = W[(size_t)(kr + ty) * H_N + nc + tx];
    __syncthreads();
    for (int ty = ty0; ty < 32; ty += 8)
      Wo[(size_t)(nc + ty) * D_N + kr + tx] = f2bf(tile[tx][ty]);
  } else {
    int b = blk - 768;
    const float4* xv = (const float4*)x;
#pragma unroll
    for (int u = 0; u < 4; ++u) {
      int i = b * 1024 + u * 256 + tid;
      float4 v = xv[i];
      ushort4 o;
      o.x = f2bf(v.x); o.y = f2bf(v.y); o.z = f2bf(v.z); o.w = f2bf(v.w);
      ((ushort4*)xb)[i] = o;
    }
  }
}

// ---------------------------------------------------------------------------
// gemm_act v3: BM=64 x BN=512 (full row, fused softmax/tanh), BK=32,
// 16 K-steps, 8 waves x (64x64) wave-tiles.
// LDS: A dbuf 2x4KB @0, B dbuf 2x32KB @8192, reduction scratch 4KB @73728
//   => 76 KB -> 2 blocks/CU (__launch_bounds__(512,4)).
// Schedule (T3+T4): STAGE(t+1) -> counted vmcnt (5 for A-staging waves 0-3,
// 4 for waves 4-7; never 0 mid-loop) -> barrier -> COMPUTE -> barrier.
// Each stage gets a FULL K-step of latency cover, and the second resident
// block fills remaining stalls.
// Swizzle (64B rows): phys slot = g ^ ((row>>1)&3); inverse applied to the
// per-lane GLOBAL source of global_load_lds (linear LDS dest, rule 21).
// <=2-way bank aliasing (free per m136).
// ---------------------------------------------------------------------------
__global__ __launch_bounds__(512, 4) void gemm_act(
    const unsigned short* __restrict__ xb,
    const unsigned short* __restrict__ Wt,
    const float* __restrict__ bDu,
    const float* __restrict__ bDr1,
    const float* __restrict__ bDr2,
    float* __restrict__ uP,
    unsigned short* __restrict__ r1P,
    unsigned short* __restrict__ r2P) {
  __shared__ __align__(16) char smem[77824];

  const int tid = threadIdx.x;
  const int lane = tid & 63;
  const int wv = tid >> 6;      // 0..7 -> column strip
  const int g = lane >> 4;      // 0..3 (16B k-chunk)
  const int c16 = lane & 15;

  const int m0 = blockIdx.x * 64;
  const int id = blockIdx.y;
  const unsigned short* Wp = Wt + (size_t)id * (D_N * H_N);

  f32x4 acc[4][4];
#pragma unroll
  for (int mt = 0; mt < 4; ++mt)
#pragma unroll
    for (int nt = 0; nt < 4; ++nt)
      acc[mt][nt] = (f32x4){0.f, 0.f, 0.f, 0.f};

  // --- staging source addresses (pre-swizzled global, linear LDS dest) ---
  // B instr jj: LDS cell n = wv*64 + jj*16 + (lane>>2), phys slot lane&3.
  // Cell (n,s) must hold k-chunk s ^ ((n>>1)&3).  (n>>1)&3 is invariant in jj.
  const int nb = wv * 64 + (lane >> 2);
  const int sb = (lane & 3) ^ ((nb >> 1) & 3);
  const unsigned short* bSrc = Wp + (size_t)nb * D_N + sb * 8;
  // A instr (waves 0..3): LDS cell na = wv*16 + (lane>>2), slot lane&3.
  const int na = (wv & 3) * 16 + (lane >> 2);
  const int sa = (lane & 3) ^ ((na >> 1) & 3);
  const unsigned short* aSrc = xb + (size_t)(m0 + na) * D_N + sa * 8;

  // read-side swizzled 16B slot offset: same for all fragments of this lane
  const int sr = (g ^ ((c16 >> 1) & 3)) << 4;

#define STAGE(buf, kstep) do {                                          \
    const int k0_ = (kstep) * 32;                                       \
    _Pragma("unroll")                                                   \
    for (int jj = 0; jj < 4; ++jj)                                      \
      GLOAD16(bSrc + (size_t)jj * (16 * D_N) + k0_,                     \
              smem + 8192 + (buf) * 32768 + wv * 4096 + jj * 1024);     \
    if (wv < 4)                                                         \
      GLOAD16(aSrc + k0_, smem + (buf) * 4096 + wv * 1024);             \
  } while (0)

#define COMPUTE(buf) do {                                               \
    bf16x8 af[4], bb[4];                                                \
    _Pragma("unroll")                                                   \
    for (int mt = 0; mt < 4; ++mt)                                      \
      af[mt] = *(const bf16x8*)(smem + (buf) * 4096 +                   \
                                (mt * 16 + c16) * 64 + sr);             \
    _Pragma("unroll")                                                   \
    for (int nt = 0; nt < 4; ++nt)                                      \
      bb[nt] = *(const bf16x8*)(smem + 8192 + (buf) * 32768 +           \
                                (wv * 64 + nt * 16 + c16) * 64 + sr);   \
    __builtin_amdgcn_s_setprio(1);                                      \
    _Pragma("unroll")                                                   \
    for (int mt = 0; mt < 4; ++mt)                                      \
      _Pragma("unroll")                                                 \
      for (int nt = 0; nt < 4; ++nt)                                    \
        acc[mt][nt] = __builtin_amdgcn_mfma_f32_16x16x32_bf16(          \
            af[mt], bb[nt], acc[mt][nt], 0, 0, 0);                      \
    __builtin_amdgcn_s_setprio(0);                                      \
  } while (0)

  STAGE(0, 0);
#pragma unroll
  for (int t = 0; t < 16; ++t) {
    const int buf = t & 1;
    if (t < 15) {
      STAGE(buf ^ 1, t + 1);
      // counted wait: leave this step's prefetch (5 or 4 instrs) in flight,
      // guarantee the current buffer's loads (issued a full K-step ago) landed
      if (wv < 4) asm volatile("s_waitcnt vmcnt(5)" ::: "memory");
      else        asm volatile("s_waitcnt vmcnt(4)" ::: "memory");
    } else {
      asm volatile("s_waitcnt vmcnt(0)" ::: "memory");
    }
    __syncthreads();
    COMPUTE(buf);
    __syncthreads();
  }

  // ---- epilogue ----
  const int colbase = wv * 64;
  const float* bp = (id == 0) ? bDu : (id == 1) ? bDr1 : bDr2;
  float bias[4];
#pragma unroll
  for (int nt = 0; nt < 4; ++nt) bias[nt] = bp[colbase + nt * 16 + c16];

  if (id == 0) {
#pragma unroll
    for (int mt = 0; mt < 4; ++mt)
#pragma unroll
      for (int i = 0; i < 4; ++i) {
        int row = m0 + mt * 16 + g * 4 + i;
        float* op = uP + (size_t)row * H_N + colbase + c16;
#pragma unroll
        for (int nt = 0; nt < 4; ++nt)
          op[nt * 16] = tanhf(acc[mt][nt][i] + bias[nt]);
      }
  } else {
    float* red  = (float*)(smem + 73728);  // [64][8]
    float* red2 = red + 512;               // [64][8]
    unsigned short* rP = (id == 1) ? r1P : r2P;
#pragma unroll
    for (int mt = 0; mt < 4; ++mt)
#pragma unroll
      for (int i = 0; i < 4; ++i) {
        float m = -3.0e38f;
#pragma unroll
        for (int nt = 0; nt < 4; ++nt) m = fmaxf(m, acc[mt][nt][i] + bias[nt]);
        m = fmaxf(m, __shfl_xor(m, 1));
        m = fmaxf(m, __shfl_xor(m, 2));
        m = fmaxf(m, __shfl_xor(m, 4));
        m = fmaxf(m, __shfl_xor(m, 8));
        if (c16 == 0) red[(mt * 16 + g * 4 + i) * 8 + wv] = m;
      }
    __syncthreads();
#pragma unroll
    for (int mt = 0; mt < 4; ++mt)
#pragma unroll
      for (int i = 0; i < 4; ++i) {
        int rl = mt * 16 + g * 4 + i;
        float4 q0 = *(const float4*)(red + rl * 8);
        float4 q1 = *(const float4*)(red + rl * 8 + 4);
        float m = fmaxf(fmaxf(fmaxf(q0.x, q0.y), fmaxf(q0.z, q0.w)),
                        fmaxf(fmaxf(q1.x, q1.y), fmaxf(q1.z, q1.w)));
        float s = 0.f;
#pragma unroll
        for (int nt = 0; nt < 4; ++nt) {
          float e = __expf(acc[mt][nt][i] + bias[nt] - m);
          acc[mt][nt][i] = e;
          s += e;
        }
        s += __shfl_xor(s, 1);
        s += __shfl_xor(s, 2);
        s += __shfl_xor(s, 4);
        s += __shfl_xor(s, 8);
        if (c16 == 0) red2[rl * 8 + wv] = s;
      }
    __syncthreads();
#pragma unroll
    for (int mt = 0; mt < 4; ++mt)
#pragma unroll
      for (int i = 0; i < 4; ++i) {
        int rl = mt * 16 + g * 4 + i;
        float4 q0 = *(const float4*)(red2 + rl * 8);
        float4 q1 = *(const float4*)(red2 + rl * 8 + 4);
        float inv = 1.f / (q0.x + q0.y + q0.z + q0.w + q1.x + q1.y + q1.z + q1.w);
        unsigned short* op = rP + (size_t)(m0 + rl) * H_N + colbase + c16;
#pragma unroll
        for (int nt = 0; nt < 4; ++nt)
          op[nt * 16] = f2bf(acc[mt][nt][i] * inv);
      }
  }
#undef STAGE
#undef COMPUTE
}

// ---------------------------------------------------------------------------
// Chunked linear-recurrence scan: s_t = r1_t * s_{t-1} + r2_t * u_t.
// 8 chunks of 64 steps; pass3 composes its own carry from cP/cS (pass2 fused).
// ---------------------------------------------------------------------------
__global__ void scan_pass1(const unsigned short* __restrict__ r1P,
                           const unsigned short* __restrict__ r2P,
                           const float* __restrict__ uP,
                           float* __restrict__ cP,
                           float* __restrict__ cS) {
  int gt = blockIdx.x * 256 + threadIdx.x;  // 0..131071
  int chunk = gt >> 14;
  int r = gt & 16383;
  int b = r >> 9, h = r & 511;
  size_t idx = (size_t)b * (T_N * H_N) + (size_t)(chunk * 64) * H_N + h;
  float p = 1.f, s = 0.f;
#pragma unroll 4
  for (int j = 0; j < 64; ++j) {
    float a = bf2f(r1P[idx]);
    float c = bf2f(r2P[idx]);
    float uu = uP[idx];
    s = fmaf(a, s, c * uu);
    p *= a;
    idx += H_N;
  }
  cP[gt] = p;
  cS[gt] = s;
}

__global__ void scan_pass3(const unsigned short* __restrict__ r1P,
                           const unsigned short* __restrict__ r2P,
                           const float* __restrict__ uP,
                           const float* __restrict__ cP,
                           const float* __restrict__ cS,
                           float* __restrict__ out) {
  int gt = blockIdx.x * 256 + threadIdx.x;
  int chunk = gt >> 14;
  int r = gt & 16383;
  int b = r >> 9, h = r & 511;
  // carry: compose preceding chunks (uniform trip count per block)
  float s = 0.f;
  for (int c2 = 0; c2 < chunk; ++c2)
    s = fmaf(cP[c2 * 16384 + r], s, cS[c2 * 16384 + r]);
  size_t idx = (size_t)b * (T_N * H_N) + (size_t)(chunk * 64) * H_N + h;
#pragma unroll 4
  for (int j = 0; j < 64; ++j) {
    float a = bf2f(r1P[idx]);
    float c = bf2f(r2P[idx]);
    float uu = uP[idx];
    s = fmaf(a, s, c * uu);
    out[idx] = s;
    idx += H_N;
  }
}

extern "C" void kernel_launch(void* const* d_in, const int* in_sizes, int n_in,
                              void* d_out, int out_size, void* d_ws, size_t ws_size,
                              hipStream_t stream) {
  const float* x  = (const float*)d_in[0];
  const float* W0 = (const float*)d_in[1];
  const float* W1 = (const float*)d_in[2];
  const float* W2 = (const float*)d_in[3];
  const float* b0 = (const float*)d_in[4];
  const float* b1 = (const float*)d_in[5];
  const float* b2 = (const float*)d_in[6];
  float* out = (float*)d_out;

  char* ws = (char*)d_ws;
  unsigned short* xb  = (unsigned short*)ws;                  // 16 MB  bf16 x
  unsigned short* Wt  = (unsigned short*)(ws + 16777216);     // 1.5 MB bf16 W^T x3
  float*          uP  = (float*)(ws + 18350080);              // 32 MB  f32 u
  unsigned short* r1P = (unsigned short*)(ws + 51904512);     // 16 MB  bf16 r1
  unsigned short* r2P = (unsigned short*)(ws + 68681728);     // 16 MB  bf16 r2
  float*          cP  = (float*)(ws + 85458944);              // 0.5 MB chunk prod
  float*          cS  = (float*)(ws + 85983232);              // 0.5 MB chunk partial
  // total 86,507,520 bytes

  prep_kernel<<<2816, 256, 0, stream>>>(x, W0, W1, W2, xb, Wt);
  gemm_act<<<dim3(256, 3), 512, 0, stream>>>(xb, Wt, b0, b1, b2, uP, r1P, r2P);
  scan_pass1<<<512, 256, 0, stream>>>(r1P, r2P, uP, cP, cS);
  scan_pass3<<<512, 256, 0, stream>>>(r1P, r2P, uP, cP, cS, out);
}

// Round 5
// 123.248 us; speedup vs baseline: 1.0028x; 1.0028x over previous
//
#include <hip/hip_runtime.h>
#include <hip/hip_bf16.h>

#define B_N 32
#define T_N 512
#define D_N 512
#define H_N 512
#define M_N (B_N * T_N)   // 16384

typedef __attribute__((ext_vector_type(8))) short bf16x8;
typedef __attribute__((ext_vector_type(4))) float f32x4;

__device__ __forceinline__ unsigned short f2bf(float f) {
  unsigned u = __float_as_uint(f);
  u += 0x7FFFu + ((u >> 16) & 1u);   // RTNE
  return (unsigned short)(u >> 16);
}
__device__ __forceinline__ float bf2f(unsigned short h) {
  return __uint_as_float(((unsigned)h) << 16);
}

#define GLOAD16(g, l) __builtin_amdgcn_global_load_lds( \
    (const __attribute__((address_space(1))) void*)(g), \
    (__attribute__((address_space(3))) void*)(l), 16, 0, 0)

// ---------------------------------------------------------------------------
// prep: blocks [0,768) transpose+convert the 3 weight matrices (W[k][n] ->
// Wt[id][n][k] bf16); blocks [768, 2816) convert x f32 -> bf16.
// ---------------------------------------------------------------------------
__global__ void prep_kernel(const float* __restrict__ x,
                            const float* __restrict__ W0,
                            const float* __restrict__ W1,
                            const float* __restrict__ W2,
                            unsigned short* __restrict__ xb,
                            unsigned short* __restrict__ Wt) {
  int blk = blockIdx.x;
  int tid = threadIdx.x;
  if (blk < 768) {
    __shared__ float tile[32][33];
    int id = blk >> 8;
    int t = blk & 255;
    int kr = (t >> 4) << 5;
    int nc = (t & 15) << 5;
    const float* W = (id == 0) ? W0 : (id == 1) ? W1 : W2;
    unsigned short* Wo = Wt + (size_t)id * (D_N * H_N);
    int tx = tid & 31, ty0 = tid >> 5;
    for (int ty = ty0; ty < 32; ty += 8)
      tile[ty][tx] = W[(size_t)(kr + ty) * H_N + nc + tx];
    __syncthreads();
    for (int ty = ty0; ty < 32; ty += 8)
      Wo[(size_t)(nc + ty) * D_N + kr + tx] = f2bf(tile[tx][ty]);
  } else {
    int b = blk - 768;
    const float4* xv = (const float4*)x;
#pragma unroll
    for (int u = 0; u < 4; ++u) {
      int i = b * 1024 + u * 256 + tid;
      float4 v = xv[i];
      ushort4 o;
      o.x = f2bf(v.x); o.y = f2bf(v.y); o.z = f2bf(v.z); o.w = f2bf(v.w);
      ((ushort4*)xb)[i] = o;
    }
  }
}

// ---------------------------------------------------------------------------
// gemm_act v4: BM=64 x BN=512 (full row, fused softmax/tanh), BK=32,
// 16 K-steps, 8 waves x (64x64) wave-tiles.  LDS 76KB -> 2 blocks/CU target.
// v3 lesson: at the 128-reg cap (launch_bounds 512,4) the in-loop peak
// (acc 64 + af[4]+bb[4] 32 + addressing) spilled ~6 regs -> 78MB scratch
// writes.  v4 restructures COMPUTE: bb[4] resident (16), af STREAMED one at
// a time (4) -> peak fragment regs 32 -> 20, fitting the cap with no spill.
// Schedule (T3+T4): STAGE(t+1) -> counted vmcnt (5/4, never 0 mid-loop) ->
// barrier -> COMPUTE -> barrier.  Full K-step of prefetch cover + 2nd
// resident block fills remaining stalls.
// Swizzle (64B rows, verified v3): phys slot = g ^ ((row>>1)&3); inverse
// applied to per-lane GLOBAL source (linear LDS dest, rule 21).
// ---------------------------------------------------------------------------
__global__ __launch_bounds__(512, 4) void gemm_act(
    const unsigned short* __restrict__ xb,
    const unsigned short* __restrict__ Wt,
    const float* __restrict__ bDu,
    const float* __restrict__ bDr1,
    const float* __restrict__ bDr2,
    float* __restrict__ uP,
    unsigned short* __restrict__ r1P,
    unsigned short* __restrict__ r2P) {
  __shared__ __align__(16) char smem[77824];

  const int tid = threadIdx.x;
  const int lane = tid & 63;
  const int wv = tid >> 6;      // 0..7 -> column strip
  const int g = lane >> 4;      // 0..3 (16B k-chunk)
  const int c16 = lane & 15;

  const int m0 = blockIdx.x * 64;
  const int id = blockIdx.y;
  const unsigned short* Wp = Wt + (size_t)id * (D_N * H_N);

  f32x4 acc[4][4];
#pragma unroll
  for (int mt = 0; mt < 4; ++mt)
#pragma unroll
    for (int nt = 0; nt < 4; ++nt)
      acc[mt][nt] = (f32x4){0.f, 0.f, 0.f, 0.f};

  // --- staging source addresses (pre-swizzled global, linear LDS dest) ---
  const int nb = wv * 64 + (lane >> 2);
  const int sb = (lane & 3) ^ ((nb >> 1) & 3);
  const unsigned short* bSrc = Wp + (size_t)nb * D_N + sb * 8;
  const int na = (wv & 3) * 16 + (lane >> 2);
  const int sa = (lane & 3) ^ ((na >> 1) & 3);
  const unsigned short* aSrc = xb + (size_t)(m0 + na) * D_N + sa * 8;

  // read-side swizzled 16B slot offset (same for all fragments of this lane)
  const int sr = (g ^ ((c16 >> 1) & 3)) << 4;

#define STAGE(buf, kstep) do {                                          \
    const int k0_ = (kstep) * 32;                                       \
    _Pragma("unroll")                                                   \
    for (int jj = 0; jj < 4; ++jj)                                      \
      GLOAD16(bSrc + (size_t)jj * (16 * D_N) + k0_,                     \
              smem + 8192 + (buf) * 32768 + wv * 4096 + jj * 1024);     \
    if (wv < 4)                                                         \
      GLOAD16(aSrc + k0_, smem + (buf) * 4096 + wv * 1024);             \
  } while (0)

#define COMPUTE(buf) do {                                               \
    bf16x8 bb[4];                                                       \
    _Pragma("unroll")                                                   \
    for (int nt = 0; nt < 4; ++nt)                                      \
      bb[nt] = *(const bf16x8*)(smem + 8192 + (buf) * 32768 +           \
                                (wv * 64 + nt * 16 + c16) * 64 + sr);   \
    __builtin_amdgcn_s_setprio(1);                                      \
    _Pragma("unroll")                                                   \
    for (int mt = 0; mt < 4; ++mt) {                                    \
      bf16x8 af = *(const bf16x8*)(smem + (buf) * 4096 +                \
                                   (mt * 16 + c16) * 64 + sr);          \
      _Pragma("unroll")                                                 \
      for (int nt = 0; nt < 4; ++nt)                                    \
        acc[mt][nt] = __builtin_amdgcn_mfma_f32_16x16x32_bf16(          \
            af, bb[nt], acc[mt][nt], 0, 0, 0);                          \
    }                                                                   \
    __builtin_amdgcn_s_setprio(0);                                      \
  } while (0)

  STAGE(0, 0);
#pragma unroll
  for (int t = 0; t < 16; ++t) {
    const int buf = t & 1;
    if (t < 15) {
      STAGE(buf ^ 1, t + 1);
      // counted wait: leave next step's prefetch (5 or 4 instrs) in flight,
      // guarantee current buffer's loads (issued a full K-step ago) landed
      if (wv < 4) asm volatile("s_waitcnt vmcnt(5)" ::: "memory");
      else        asm volatile("s_waitcnt vmcnt(4)" ::: "memory");
    } else {
      asm volatile("s_waitcnt vmcnt(0)" ::: "memory");
    }
    __syncthreads();
    COMPUTE(buf);
    __syncthreads();
  }

  // ---- epilogue ----
  const int colbase = wv * 64;
  const float* bp = (id == 0) ? bDu : (id == 1) ? bDr1 : bDr2;
  float bias[4];
#pragma unroll
  for (int nt = 0; nt < 4; ++nt) bias[nt] = bp[colbase + nt * 16 + c16];

  if (id == 0) {
#pragma unroll
    for (int mt = 0; mt < 4; ++mt)
#pragma unroll
      for (int i = 0; i < 4; ++i) {
        int row = m0 + mt * 16 + g * 4 + i;
        float* op = uP + (size_t)row * H_N + colbase + c16;
#pragma unroll
        for (int nt = 0; nt < 4; ++nt)
          op[nt * 16] = tanhf(acc[mt][nt][i] + bias[nt]);
      }
  } else {
    float* red  = (float*)(smem + 73728);  // [64][8]
    float* red2 = red + 512;               // [64][8]
    unsigned short* rP = (id == 1) ? r1P : r2P;
#pragma unroll
    for (int mt = 0; mt < 4; ++mt)
#pragma unroll
      for (int i = 0; i < 4; ++i) {
        float m = -3.0e38f;
#pragma unroll
        for (int nt = 0; nt < 4; ++nt) m = fmaxf(m, acc[mt][nt][i] + bias[nt]);
        m = fmaxf(m, __shfl_xor(m, 1));
        m = fmaxf(m, __shfl_xor(m, 2));
        m = fmaxf(m, __shfl_xor(m, 4));
        m = fmaxf(m, __shfl_xor(m, 8));
        if (c16 == 0) red[(mt * 16 + g * 4 + i) * 8 + wv] = m;
      }
    __syncthreads();
#pragma unroll
    for (int mt = 0; mt < 4; ++mt)
#pragma unroll
      for (int i = 0; i < 4; ++i) {
        int rl = mt * 16 + g * 4 + i;
        float4 q0 = *(const float4*)(red + rl * 8);
        float4 q1 = *(const float4*)(red + rl * 8 + 4);
        float m = fmaxf(fmaxf(fmaxf(q0.x, q0.y), fmaxf(q0.z, q0.w)),
                        fmaxf(fmaxf(q1.x, q1.y), fmaxf(q1.z, q1.w)));
        float s = 0.f;
#pragma unroll
        for (int nt = 0; nt < 4; ++nt) {
          float e = __expf(acc[mt][nt][i] + bias[nt] - m);
          acc[mt][nt][i] = e;
          s += e;
        }
        s += __shfl_xor(s, 1);
        s += __shfl_xor(s, 2);
        s += __shfl_xor(s, 4);
        s += __shfl_xor(s, 8);
        if (c16 == 0) red2[rl * 8 + wv] = s;
      }
    __syncthreads();
#pragma unroll
    for (int mt = 0; mt < 4; ++mt)
#pragma unroll
      for (int i = 0; i < 4; ++i) {
        int rl = mt * 16 + g * 4 + i;
        float4 q0 = *(const float4*)(red2 + rl * 8);
        float4 q1 = *(const float4*)(red2 + rl * 8 + 4);
        float inv = 1.f / (q0.x + q0.y + q0.z + q0.w + q1.x + q1.y + q1.z + q1.w);
        unsigned short* op = rP + (size_t)(m0 + rl) * H_N + colbase + c16;
#pragma unroll
        for (int nt = 0; nt < 4; ++nt)
          op[nt * 16] = f2bf(acc[mt][nt][i] * inv);
      }
  }
#undef STAGE
#undef COMPUTE
}

// ---------------------------------------------------------------------------
// Chunked linear-recurrence scan: s_t = r1_t * s_{t-1} + r2_t * u_t.
// 8 chunks of 64 steps; pass3 composes its own carry from cP/cS (pass2 fused).
// ---------------------------------------------------------------------------
__global__ void scan_pass1(const unsigned short* __restrict__ r1P,
                           const unsigned short* __restrict__ r2P,
                           const float* __restrict__ uP,
                           float* __restrict__ cP,
                           float* __restrict__ cS) {
  int gt = blockIdx.x * 256 + threadIdx.x;  // 0..131071
  int chunk = gt >> 14;
  int r = gt & 16383;
  int b = r >> 9, h = r & 511;
  size_t idx = (size_t)b * (T_N * H_N) + (size_t)(chunk * 64) * H_N + h;
  float p = 1.f, s = 0.f;
#pragma unroll 4
  for (int j = 0; j < 64; ++j) {
    float a = bf2f(r1P[idx]);
    float c = bf2f(r2P[idx]);
    float uu = uP[idx];
    s = fmaf(a, s, c * uu);
    p *= a;
    idx += H_N;
  }
  cP[gt] = p;
  cS[gt] = s;
}

__global__ void scan_pass3(const unsigned short* __restrict__ r1P,
                           const unsigned short* __restrict__ r2P,
                           const float* __restrict__ uP,
                           const float* __restrict__ cP,
                           const float* __restrict__ cS,
                           float* __restrict__ out) {
  int gt = blockIdx.x * 256 + threadIdx.x;
  int chunk = gt >> 14;
  int r = gt & 16383;
  int b = r >> 9, h = r & 511;
  // carry: compose preceding chunks (uniform trip count per block)
  float s = 0.f;
  for (int c2 = 0; c2 < chunk; ++c2)
    s = fmaf(cP[c2 * 16384 + r], s, cS[c2 * 16384 + r]);
  size_t idx = (size_t)b * (T_N * H_N) + (size_t)(chunk * 64) * H_N + h;
#pragma unroll 4
  for (int j = 0; j < 64; ++j) {
    float a = bf2f(r1P[idx]);
    float c = bf2f(r2P[idx]);
    float uu = uP[idx];
    s = fmaf(a, s, c * uu);
    out[idx] = s;
    idx += H_N;
  }
}

extern "C" void kernel_launch(void* const* d_in, const int* in_sizes, int n_in,
                              void* d_out, int out_size, void* d_ws, size_t ws_size,
                              hipStream_t stream) {
  const float* x  = (const float*)d_in[0];
  const float* W0 = (const float*)d_in[1];
  const float* W1 = (const float*)d_in[2];
  const float* W2 = (const float*)d_in[3];
  const float* b0 = (const float*)d_in[4];
  const float* b1 = (const float*)d_in[5];
  const float* b2 = (const float*)d_in[6];
  float* out = (float*)d_out;

  char* ws = (char*)d_ws;
  unsigned short* xb  = (unsigned short*)ws;                  // 16 MB  bf16 x
  unsigned short* Wt  = (unsigned short*)(ws + 16777216);     // 1.5 MB bf16 W^T x3
  float*          uP  = (float*)(ws + 18350080);              // 32 MB  f32 u
  unsigned short* r1P = (unsigned short*)(ws + 51904512);     // 16 MB  bf16 r1
  unsigned short* r2P = (unsigned short*)(ws + 68681728);     // 16 MB  bf16 r2
  float*          cP  = (float*)(ws + 85458944);              // 0.5 MB chunk prod
  float*          cS  = (float*)(ws + 85983232);              // 0.5 MB chunk partial
  // total 86,507,520 bytes

  prep_kernel<<<2816, 256, 0, stream>>>(x, W0, W1, W2, xb, Wt);
  gemm_act<<<dim3(256, 3), 512, 0, stream>>>(xb, Wt, b0, b1, b2, uP, r1P, r2P);
  scan_pass1<<<512, 256, 0, stream>>>(r1P, r2P, uP, cP, cS);
  scan_pass3<<<512, 256, 0, stream>>>(r1P, r2P, uP, cP, cS, out);
}

// Round 6
// 121.472 us; speedup vs baseline: 1.0175x; 1.0146x over previous
//
#include <hip/hip_runtime.h>
#include <hip/hip_bf16.h>

#define B_N 32
#define T_N 512
#define D_N 512
#define H_N 512
#define M_N (B_N * T_N)   // 16384

typedef __attribute__((ext_vector_type(8))) short bf16x8;
typedef __attribute__((ext_vector_type(4))) float f32x4;

__device__ __forceinline__ unsigned short f2bf(float f) {
  unsigned u = __float_as_uint(f);
  u += 0x7FFFu + ((u >> 16) & 1u);   // RTNE
  return (unsigned short)(u >> 16);
}
__device__ __forceinline__ float bf2f(unsigned short h) {
  return __uint_as_float(((unsigned)h) << 16);
}

#define GLOAD16(g, l) __builtin_amdgcn_global_load_lds( \
    (const __attribute__((address_space(1))) void*)(g), \
    (__attribute__((address_space(3))) void*)(l), 16, 0, 0)

// ---------------------------------------------------------------------------
// prep: blocks [0,768) transpose+convert the 3 weight matrices (W[k][n] ->
// Wt[id][n][k] bf16); blocks [768, 2816) convert x f32 -> bf16.
// ---------------------------------------------------------------------------
__global__ void prep_kernel(const float* __restrict__ x,
                            const float* __restrict__ W0,
                            const float* __restrict__ W1,
                            const float* __restrict__ W2,
                            unsigned short* __restrict__ xb,
                            unsigned short* __restrict__ Wt) {
  int blk = blockIdx.x;
  int tid = threadIdx.x;
  if (blk < 768) {
    __shared__ float tile[32][33];
    int id = blk >> 8;
    int t = blk & 255;
    int kr = (t >> 4) << 5;
    int nc = (t & 15) << 5;
    const float* W = (id == 0) ? W0 : (id == 1) ? W1 : W2;
    unsigned short* Wo = Wt + (size_t)id * (D_N * H_N);
    int tx = tid & 31, ty0 = tid >> 5;
    for (int ty = ty0; ty < 32; ty += 8)
      tile[ty][tx] = W[(size_t)(kr + ty) * H_N + nc + tx];
    __syncthreads();
    for (int ty = ty0; ty < 32; ty += 8)
      Wo[(size_t)(nc + ty) * D_N + kr + tx] = f2bf(tile[tx][ty]);
  } else {
    int b = blk - 768;
    const float4* xv = (const float4*)x;
#pragma unroll
    for (int u = 0; u < 4; ++u) {
      int i = b * 1024 + u * 256 + tid;
      float4 v = xv[i];
      ushort4 o;
      o.x = f2bf(v.x); o.y = f2bf(v.y); o.z = f2bf(v.z); o.w = f2bf(v.w);
      ((ushort4*)xb)[i] = o;
    }
  }
}

// ---------------------------------------------------------------------------
// gemm_act v5: BM=64 x BN=512 (fused softmax/tanh), BK=32, 16 K-steps,
// 8 waves x (64x64) wave-tiles.  LDS 76KB -> 2 blocks/CU.
// v4 lesson: the FULLY-UNROLLED 16-step K-loop let the scheduler hoist
// cross-iteration ds_reads/addressing -> peak liveness > 128-reg cap ->
// 107MB scratch spill traffic.  v5 ROLLS the loop (#pragma unroll 1, 7
// iterations x {buf0,buf1} static body + 2-step tail); barriers at body
// boundaries bound liveness.  Wait invariant: at each WAITP outstanding =
// 2 stages -> vmcnt(5/4) drains exactly the previous stage (T4, never 0
// mid-loop); tail drains once.
// Swizzle (64B rows, verified v3): phys slot = g ^ ((row>>1)&3); inverse
// applied to per-lane GLOBAL source (linear LDS dest, rule 21).
// ---------------------------------------------------------------------------
__global__ __launch_bounds__(512, 4) void gemm_act(
    const unsigned short* __restrict__ xb,
    const unsigned short* __restrict__ Wt,
    const float* __restrict__ bDu,
    const float* __restrict__ bDr1,
    const float* __restrict__ bDr2,
    float* __restrict__ uP,
    unsigned short* __restrict__ r1P,
    unsigned short* __restrict__ r2P) {
  __shared__ __align__(16) char smem[77824];

  const int tid = threadIdx.x;
  const int lane = tid & 63;
  const int wv = tid >> 6;      // 0..7 -> column strip
  const int g = lane >> 4;      // 0..3 (16B k-chunk)
  const int c16 = lane & 15;

  const int m0 = blockIdx.x * 64;
  const int id = blockIdx.y;
  const unsigned short* Wp = Wt + (size_t)id * (D_N * H_N);

  f32x4 acc[4][4];
#pragma unroll
  for (int mt = 0; mt < 4; ++mt)
#pragma unroll
    for (int nt = 0; nt < 4; ++nt)
      acc[mt][nt] = (f32x4){0.f, 0.f, 0.f, 0.f};

  // --- staging source addresses (pre-swizzled global, linear LDS dest) ---
  const int nb = wv * 64 + (lane >> 2);
  const int sb = (lane & 3) ^ ((nb >> 1) & 3);
  const unsigned short* bSrc = Wp + (size_t)nb * D_N + sb * 8;
  const int na = (wv & 3) * 16 + (lane >> 2);
  const int sa = (lane & 3) ^ ((na >> 1) & 3);
  const unsigned short* aSrc = xb + (size_t)(m0 + na) * D_N + sa * 8;

  // read-side swizzled 16B slot offset (same for all fragments of this lane)
  const int sr = (g ^ ((c16 >> 1) & 3)) << 4;

#define STAGE(buf, kstep) do {                                          \
    const int k0_ = (kstep) * 32;                                       \
    _Pragma("unroll")                                                   \
    for (int jj = 0; jj < 4; ++jj)                                      \
      GLOAD16(bSrc + (size_t)jj * (16 * D_N) + k0_,                     \
              smem + 8192 + (buf) * 32768 + wv * 4096 + jj * 1024);     \
    if (wv < 4)                                                         \
      GLOAD16(aSrc + k0_, smem + (buf) * 4096 + wv * 1024);             \
  } while (0)

#define WAITP do {                                                      \
    if (wv < 4) asm volatile("s_waitcnt vmcnt(5)" ::: "memory");        \
    else        asm volatile("s_waitcnt vmcnt(4)" ::: "memory");        \
  } while (0)

#define COMPUTE(buf) do {                                               \
    bf16x8 bb[4];                                                       \
    _Pragma("unroll")                                                   \
    for (int nt = 0; nt < 4; ++nt)                                      \
      bb[nt] = *(const bf16x8*)(smem + 8192 + (buf) * 32768 +           \
                                (wv * 64 + nt * 16 + c16) * 64 + sr);   \
    __builtin_amdgcn_s_setprio(1);                                      \
    _Pragma("unroll")                                                   \
    for (int mt = 0; mt < 4; ++mt) {                                    \
      bf16x8 af = *(const bf16x8*)(smem + (buf) * 4096 +                \
                                   (mt * 16 + c16) * 64 + sr);          \
      _Pragma("unroll")                                                 \
      for (int nt = 0; nt < 4; ++nt)                                    \
        acc[mt][nt] = __builtin_amdgcn_mfma_f32_16x16x32_bf16(          \
            af, bb[nt], acc[mt][nt], 0, 0, 0);                          \
    }                                                                   \
    __builtin_amdgcn_s_setprio(0);                                      \
  } while (0)

  STAGE(0, 0);
#pragma unroll 1
  for (int i = 0; i < 7; ++i) {
    STAGE(1, 2 * i + 1);
    WAITP;
    __syncthreads();
    COMPUTE(0);
    __syncthreads();
    STAGE(0, 2 * i + 2);
    WAITP;
    __syncthreads();
    COMPUTE(1);
    __syncthreads();
  }
  // tail: steps 14 (buf0) and 15 (buf1)
  STAGE(1, 15);
  WAITP;
  __syncthreads();
  COMPUTE(0);
  __syncthreads();
  asm volatile("s_waitcnt vmcnt(0)" ::: "memory");
  __syncthreads();
  COMPUTE(1);

  // ---- epilogue ----
  const int colbase = wv * 64;
  const float* bp = (id == 0) ? bDu : (id == 1) ? bDr1 : bDr2;
  float bias[4];
#pragma unroll
  for (int nt = 0; nt < 4; ++nt) bias[nt] = bp[colbase + nt * 16 + c16];

  if (id == 0) {
#pragma unroll
    for (int mt = 0; mt < 4; ++mt)
#pragma unroll
      for (int i = 0; i < 4; ++i) {
        int row = m0 + mt * 16 + g * 4 + i;
        float* op = uP + (size_t)row * H_N + colbase + c16;
#pragma unroll
        for (int nt = 0; nt < 4; ++nt)
          op[nt * 16] = tanhf(acc[mt][nt][i] + bias[nt]);
      }
  } else {
    float* red  = (float*)(smem + 73728);  // [64][8]
    float* red2 = red + 512;               // [64][8]
    unsigned short* rP = (id == 1) ? r1P : r2P;
#pragma unroll
    for (int mt = 0; mt < 4; ++mt)
#pragma unroll
      for (int i = 0; i < 4; ++i) {
        float m = -3.0e38f;
#pragma unroll
        for (int nt = 0; nt < 4; ++nt) m = fmaxf(m, acc[mt][nt][i] + bias[nt]);
        m = fmaxf(m, __shfl_xor(m, 1));
        m = fmaxf(m, __shfl_xor(m, 2));
        m = fmaxf(m, __shfl_xor(m, 4));
        m = fmaxf(m, __shfl_xor(m, 8));
        if (c16 == 0) red[(mt * 16 + g * 4 + i) * 8 + wv] = m;
      }
    __syncthreads();
#pragma unroll
    for (int mt = 0; mt < 4; ++mt)
#pragma unroll
      for (int i = 0; i < 4; ++i) {
        int rl = mt * 16 + g * 4 + i;
        float4 q0 = *(const float4*)(red + rl * 8);
        float4 q1 = *(const float4*)(red + rl * 8 + 4);
        float m = fmaxf(fmaxf(fmaxf(q0.x, q0.y), fmaxf(q0.z, q0.w)),
                        fmaxf(fmaxf(q1.x, q1.y), fmaxf(q1.z, q1.w)));
        float s = 0.f;
#pragma unroll
        for (int nt = 0; nt < 4; ++nt) {
          float e = __expf(acc[mt][nt][i] + bias[nt] - m);
          acc[mt][nt][i] = e;
          s += e;
        }
        s += __shfl_xor(s, 1);
        s += __shfl_xor(s, 2);
        s += __shfl_xor(s, 4);
        s += __shfl_xor(s, 8);
        if (c16 == 0) red2[rl * 8 + wv] = s;
      }
    __syncthreads();
#pragma unroll
    for (int mt = 0; mt < 4; ++mt)
#pragma unroll
      for (int i = 0; i < 4; ++i) {
        int rl = mt * 16 + g * 4 + i;
        float4 q0 = *(const float4*)(red2 + rl * 8);
        float4 q1 = *(const float4*)(red2 + rl * 8 + 4);
        float inv = 1.f / (q0.x + q0.y + q0.z + q0.w + q1.x + q1.y + q1.z + q1.w);
        unsigned short* op = rP + (size_t)(m0 + rl) * H_N + colbase + c16;
#pragma unroll
        for (int nt = 0; nt < 4; ++nt)
          op[nt * 16] = f2bf(acc[mt][nt][i] * inv);
      }
  }
#undef STAGE
#undef WAITP
#undef COMPUTE
}

// ---------------------------------------------------------------------------
// Chunked linear-recurrence scan: s_t = r1_t * s_{t-1} + r2_t * u_t.
// 8 chunks of 64 steps; pass3 composes its own carry from cP/cS (pass2 fused).
// ---------------------------------------------------------------------------
__global__ void scan_pass1(const unsigned short* __restrict__ r1P,
                           const unsigned short* __restrict__ r2P,
                           const float* __restrict__ uP,
                           float* __restrict__ cP,
                           float* __restrict__ cS) {
  int gt = blockIdx.x * 256 + threadIdx.x;  // 0..131071
  int chunk = gt >> 14;
  int r = gt & 16383;
  int b = r >> 9, h = r & 511;
  size_t idx = (size_t)b * (T_N * H_N) + (size_t)(chunk * 64) * H_N + h;
  float p = 1.f, s = 0.f;
#pragma unroll 4
  for (int j = 0; j < 64; ++j) {
    float a = bf2f(r1P[idx]);
    float c = bf2f(r2P[idx]);
    float uu = uP[idx];
    s = fmaf(a, s, c * uu);
    p *= a;
    idx += H_N;
  }
  cP[gt] = p;
  cS[gt] = s;
}

__global__ void scan_pass3(const unsigned short* __restrict__ r1P,
                           const unsigned short* __restrict__ r2P,
                           const float* __restrict__ uP,
                           const float* __restrict__ cP,
                           const float* __restrict__ cS,
                           float* __restrict__ out) {
  int gt = blockIdx.x * 256 + threadIdx.x;
  int chunk = gt >> 14;
  int r = gt & 16383;
  int b = r >> 9, h = r & 511;
  // carry: compose preceding chunks (uniform trip count per block)
  float s = 0.f;
  for (int c2 = 0; c2 < chunk; ++c2)
    s = fmaf(cP[c2 * 16384 + r], s, cS[c2 * 16384 + r]);
  size_t idx = (size_t)b * (T_N * H_N) + (size_t)(chunk * 64) * H_N + h;
#pragma unroll 4
  for (int j = 0; j < 64; ++j) {
    float a = bf2f(r1P[idx]);
    float c = bf2f(r2P[idx]);
    float uu = uP[idx];
    s = fmaf(a, s, c * uu);
    out[idx] = s;
    idx += H_N;
  }
}

extern "C" void kernel_launch(void* const* d_in, const int* in_sizes, int n_in,
                              void* d_out, int out_size, void* d_ws, size_t ws_size,
                              hipStream_t stream) {
  const float* x  = (const float*)d_in[0];
  const float* W0 = (const float*)d_in[1];
  const float* W1 = (const float*)d_in[2];
  const float* W2 = (const float*)d_in[3];
  const float* b0 = (const float*)d_in[4];
  const float* b1 = (const float*)d_in[5];
  const float* b2 = (const float*)d_in[6];
  float* out = (float*)d_out;

  char* ws = (char*)d_ws;
  unsigned short* xb  = (unsigned short*)ws;                  // 16 MB  bf16 x
  unsigned short* Wt  = (unsigned short*)(ws + 16777216);     // 1.5 MB bf16 W^T x3
  float*          uP  = (float*)(ws + 18350080);              // 32 MB  f32 u
  unsigned short* r1P = (unsigned short*)(ws + 51904512);     // 16 MB  bf16 r1
  unsigned short* r2P = (unsigned short*)(ws + 68681728);     // 16 MB  bf16 r2
  float*          cP  = (float*)(ws + 85458944);              // 0.5 MB chunk prod
  float*          cS  = (float*)(ws + 85983232);              // 0.5 MB chunk partial
  // total 86,507,520 bytes

  prep_kernel<<<2816, 256, 0, stream>>>(x, W0, W1, W2, xb, Wt);
  gemm_act<<<dim3(256, 3), 512, 0, stream>>>(xb, Wt, b0, b1, b2, uP, r1P, r2P);
  scan_pass1<<<512, 256, 0, stream>>>(r1P, r2P, uP, cP, cS);
  scan_pass3<<<512, 256, 0, stream>>>(r1P, r2P, uP, cP, cS, out);
}

// Round 7
// 85.029 us; speedup vs baseline: 1.4536x; 1.4286x over previous
//
#include <hip/hip_runtime.h>
#include <hip/hip_bf16.h>

#define B_N 32
#define T_N 512
#define D_N 512
#define H_N 512
#define M_N (B_N * T_N)   // 16384

typedef __attribute__((ext_vector_type(8))) short bf16x8;   // generic 16B
typedef __attribute__((ext_vector_type(4))) float f32x4;

__device__ __forceinline__ unsigned short f2bf(float f) {
  unsigned u = __float_as_uint(f);
  u += 0x7FFFu + ((u >> 16) & 1u);   // RTNE
  return (unsigned short)(u >> 16);
}
__device__ __forceinline__ float bf2f(unsigned short h) {
  return __uint_as_float(((unsigned)h) << 16);
}
__device__ __forceinline__ unsigned short f2h(float f) {
  _Float16 h = (_Float16)f;
  return *(unsigned short*)&h;
}
__device__ __forceinline__ float h2f(unsigned short u) {
  _Float16 h = *(_Float16*)&u;
  return (float)h;
}

#define GLOAD16(g, l) __builtin_amdgcn_global_load_lds( \
    (const __attribute__((address_space(1))) void*)(g), \
    (__attribute__((address_space(3))) void*)(l), 16, 0, 0)

// ---------------------------------------------------------------------------
// prep: blocks [0,768) transpose+convert W -> Wt[id][n][k] bf16;
// blocks [768, 2816) convert x f32 -> bf16.
// ---------------------------------------------------------------------------
__global__ void prep_kernel(const float* __restrict__ x,
                            const float* __restrict__ W0,
                            const float* __restrict__ W1,
                            const float* __restrict__ W2,
                            unsigned short* __restrict__ xb,
                            unsigned short* __restrict__ Wt) {
  int blk = blockIdx.x;
  int tid = threadIdx.x;
  if (blk < 768) {
    __shared__ float tile[32][33];
    int id = blk >> 8;
    int t = blk & 255;
    int kr = (t >> 4) << 5;
    int nc = (t & 15) << 5;
    const float* W = (id == 0) ? W0 : (id == 1) ? W1 : W2;
    unsigned short* Wo = Wt + (size_t)id * (D_N * H_N);
    int tx = tid & 31, ty0 = tid >> 5;
    for (int ty = ty0; ty < 32; ty += 8)
      tile[ty][tx] = W[(size_t)(kr + ty) * H_N + nc + tx];
    __syncthreads();
    for (int ty = ty0; ty < 32; ty += 8)
      Wo[(size_t)(nc + ty) * D_N + kr + tx] = f2bf(tile[tx][ty]);
  } else {
    int b = blk - 768;
    const float4* xv = (const float4*)x;
#pragma unroll
    for (int u = 0; u < 4; ++u) {
      int i = b * 1024 + u * 256 + tid;
      float4 v = xv[i];
      ushort4 o;
      o.x = f2bf(v.x); o.y = f2bf(v.y); o.z = f2bf(v.z); o.w = f2bf(v.w);
      ((ushort4*)xb)[i] = o;
    }
  }
}

// ---------------------------------------------------------------------------
// gemm3 (m97 geometry): 128x128 tile, BK=64, 256 threads / 4 waves, each wave
// a 64x64 quadrant.  Single 32KB LDS buffer; per K-step: stage 8 GLOAD16 ->
// vmcnt(0) + barrier -> ds_read+MFMA -> barrier.  No launch_bounds cap
// (v4/v5 lesson: 128-reg cap => 77MB spill); occupancy comes from 3-4
// co-resident blocks/CU providing cross-block overlap (m114).
// Epilogue is ELEMENTWISE only (softmax decoupled): id0 -> tanh f16,
// id1/2 -> exp f16 (no max-sub needed: |z|<=~7).
// Swizzle identical to v1-verified: 128B rows, 16B slot p = s ^ (row&7),
// inverse applied to per-lane GLOBAL source (linear LDS dest).
// ---------------------------------------------------------------------------
__global__ __launch_bounds__(256) void gemm3(
    const unsigned short* __restrict__ xb,
    const unsigned short* __restrict__ Wt,
    const float* __restrict__ bDu,
    const float* __restrict__ bDr1,
    const float* __restrict__ bDr2,
    unsigned short* __restrict__ uP,
    unsigned short* __restrict__ e1P,
    unsigned short* __restrict__ e2P) {
  __shared__ __align__(16) unsigned short lA[128 * 64];
  __shared__ __align__(16) unsigned short lB[128 * 64];

  const int tid = threadIdx.x;      // 0..255
  const int lane = tid & 63;
  const int wv = tid >> 6;          // 0..3
  const int wr = wv >> 1;           // wave row (0..1)
  const int wc = wv & 1;            // wave col (0..1)
  const int g = lane >> 4;          // 0..3
  const int c16 = lane & 15;

  const int m0 = blockIdx.x * 128;
  const int n0 = blockIdx.y * 128;
  const int id = blockIdx.z;
  const unsigned short* Wp = Wt + (size_t)id * (D_N * H_N);

  f32x4 acc[4][4];
#pragma unroll
  for (int mt = 0; mt < 4; ++mt)
#pragma unroll
    for (int nt = 0; nt < 4; ++nt)
      acc[mt][nt] = (f32x4){0.f, 0.f, 0.f, 0.f};

  // staging: tile = 1024 chunks of 16B; thread handles chunks i*256+tid.
  // row = i*32 + (tid>>3); phys slot = tid&7; logical slot = (tid&7)^((tid>>3)&7)
  const int rowoff = tid >> 3;                       // 0..31
  const int lsl = ((tid & 7) ^ ((tid >> 3) & 7)) * 8;  // elems
  const unsigned short* aSrc = xb + (size_t)(m0 + rowoff) * D_N + lsl;
  const unsigned short* bSrc = Wp + (size_t)(n0 + rowoff) * D_N + lsl;
  // LDS dst base (wave-uniform part): i*4096 + wv*1024 (+ lane*16 implicit)
  char* const lAc = (char*)lA + wv * 1024;
  char* const lBc = (char*)lB + wv * 1024;

  // read-side swizzled slot offsets (row&7 == c16&7 for all fragments)
  const int h3 = c16 & 7;

#pragma unroll 1
  for (int t = 0; t < 8; ++t) {
    const int k0 = t * 64;
#pragma unroll
    for (int i = 0; i < 4; ++i)
      GLOAD16(aSrc + (size_t)i * (32 * D_N) + k0, lAc + i * 4096);
#pragma unroll
    for (int i = 0; i < 4; ++i)
      GLOAD16(bSrc + (size_t)i * (32 * D_N) + k0, lBc + i * 4096);
    asm volatile("s_waitcnt vmcnt(0)" ::: "memory");
    __syncthreads();
#pragma unroll
    for (int kh = 0; kh < 2; ++kh) {
      const int soff = ((kh * 4 + g) ^ h3) << 4;
      bf16x8 af[4], bb[4];
#pragma unroll
      for (int mt = 0; mt < 4; ++mt)
        af[mt] = *(const bf16x8*)((const char*)lA +
                                  (wr * 64 + mt * 16 + c16) * 128 + soff);
#pragma unroll
      for (int nt = 0; nt < 4; ++nt)
        bb[nt] = *(const bf16x8*)((const char*)lB +
                                  (wc * 64 + nt * 16 + c16) * 128 + soff);
#pragma unroll
      for (int mt = 0; mt < 4; ++mt)
#pragma unroll
        for (int nt = 0; nt < 4; ++nt)
          acc[mt][nt] = __builtin_amdgcn_mfma_f32_16x16x32_bf16(
              af[mt], bb[nt], acc[mt][nt], 0, 0, 0);
    }
    __syncthreads();
  }

  // ---- elementwise epilogue ----
  const float* bp = (id == 0) ? bDu : (id == 1) ? bDr1 : bDr2;
  unsigned short* outp = (id == 0) ? uP : (id == 1) ? e1P : e2P;
  float bias[4];
#pragma unroll
  for (int nt = 0; nt < 4; ++nt)
    bias[nt] = bp[n0 + wc * 64 + nt * 16 + c16];

#pragma unroll
  for (int mt = 0; mt < 4; ++mt)
#pragma unroll
    for (int i = 0; i < 4; ++i) {
      int row = m0 + wr * 64 + mt * 16 + g * 4 + i;
      unsigned short* op = outp + (size_t)row * H_N + n0 + wc * 64 + c16;
      if (id == 0) {
#pragma unroll
        for (int nt = 0; nt < 4; ++nt)
          op[nt * 16] = f2h(tanhf(acc[mt][nt][i] + bias[nt]));
      } else {
#pragma unroll
        for (int nt = 0; nt < 4; ++nt)
          op[nt * 16] = f2h(__expf(acc[mt][nt][i] + bias[nt]));
      }
    }
}

// ---------------------------------------------------------------------------
// rowsum: one wave per (b,t) row; computes 1/sum(e1) and 1/sum(e2).
// ---------------------------------------------------------------------------
__global__ void rowsum(const unsigned short* __restrict__ e1P,
                       const unsigned short* __restrict__ e2P,
                       float* __restrict__ iS1,
                       float* __restrict__ iS2) {
  int row = blockIdx.x * 4 + (threadIdx.x >> 6);
  int lane = threadIdx.x & 63;
  const bf16x8 v1 = *(const bf16x8*)(e1P + (size_t)row * H_N + lane * 8);
  const bf16x8 v2 = *(const bf16x8*)(e2P + (size_t)row * H_N + lane * 8);
  float s1 = 0.f, s2 = 0.f;
#pragma unroll
  for (int i = 0; i < 8; ++i) {
    s1 += h2f((unsigned short)v1[i]);
    s2 += h2f((unsigned short)v2[i]);
  }
#pragma unroll
  for (int d = 1; d < 64; d <<= 1) {
    s1 += __shfl_xor(s1, d);
    s2 += __shfl_xor(s2, d);
  }
  if (lane == 0) {
    iS1[row] = 1.f / s1;
    iS2[row] = 1.f / s2;
  }
}

// ---------------------------------------------------------------------------
// Chunked linear-recurrence scan: s_t = r1_t*s + r2_t*u_t, with
// r_i = e_i * invS_i applied on the fly (invS is lane-uniform -> broadcast).
// ---------------------------------------------------------------------------
__global__ void scan_pass1(const unsigned short* __restrict__ e1P,
                           const unsigned short* __restrict__ e2P,
                           const unsigned short* __restrict__ uP,
                           const float* __restrict__ iS1,
                           const float* __restrict__ iS2,
                           float* __restrict__ cP,
                           float* __restrict__ cS) {
  int gt = blockIdx.x * 256 + threadIdx.x;  // 0..131071
  int chunk = gt >> 14;
  int r = gt & 16383;
  int b = r >> 9, h = r & 511;
  int row0 = b * T_N + chunk * 64;
  size_t idx = (size_t)row0 * H_N + h;
  float p = 1.f, s = 0.f;
#pragma unroll 4
  for (int j = 0; j < 64; ++j) {
    float a = iS1[row0 + j] * h2f(e1P[idx]);
    float cu = iS2[row0 + j] * h2f(e2P[idx]) * h2f(uP[idx]);
    s = fmaf(a, s, cu);
    p *= a;
    idx += H_N;
  }
  cP[gt] = p;
  cS[gt] = s;
}

__global__ void scan_pass3(const unsigned short* __restrict__ e1P,
                           const unsigned short* __restrict__ e2P,
                           const unsigned short* __restrict__ uP,
                           const float* __restrict__ iS1,
                           const float* __restrict__ iS2,
                           const float* __restrict__ cP,
                           const float* __restrict__ cS,
                           float* __restrict__ out) {
  int gt = blockIdx.x * 256 + threadIdx.x;
  int chunk = gt >> 14;
  int r = gt & 16383;
  int b = r >> 9, h = r & 511;
  float s = 0.f;
  for (int c2 = 0; c2 < chunk; ++c2)
    s = fmaf(cP[c2 * 16384 + r], s, cS[c2 * 16384 + r]);
  int row0 = b * T_N + chunk * 64;
  size_t idx = (size_t)row0 * H_N + h;
#pragma unroll 4
  for (int j = 0; j < 64; ++j) {
    float a = iS1[row0 + j] * h2f(e1P[idx]);
    float cu = iS2[row0 + j] * h2f(e2P[idx]) * h2f(uP[idx]);
    s = fmaf(a, s, cu);
    out[idx] = s;
    idx += H_N;
  }
}

extern "C" void kernel_launch(void* const* d_in, const int* in_sizes, int n_in,
                              void* d_out, int out_size, void* d_ws, size_t ws_size,
                              hipStream_t stream) {
  const float* x  = (const float*)d_in[0];
  const float* W0 = (const float*)d_in[1];
  const float* W1 = (const float*)d_in[2];
  const float* W2 = (const float*)d_in[3];
  const float* b0 = (const float*)d_in[4];
  const float* b1 = (const float*)d_in[5];
  const float* b2 = (const float*)d_in[6];
  float* out = (float*)d_out;

  char* ws = (char*)d_ws;
  unsigned short* xb  = (unsigned short*)ws;                  // 16 MB  bf16 x
  unsigned short* Wt  = (unsigned short*)(ws + 16777216);     // 1.5 MB bf16 W^T x3
  unsigned short* uP  = (unsigned short*)(ws + 18350080);     // 16 MB  f16 tanh(u)
  unsigned short* e1P = (unsigned short*)(ws + 35127296);     // 16 MB  f16 exp(z1)
  unsigned short* e2P = (unsigned short*)(ws + 51904512);     // 16 MB  f16 exp(z2)
  float*          iS1 = (float*)(ws + 68681728);              // 64 KB  1/rowsum
  float*          iS2 = (float*)(ws + 68747264);              // 64 KB
  float*          cP  = (float*)(ws + 68812800);              // 0.5 MB chunk prod
  float*          cS  = (float*)(ws + 69337088);              // 0.5 MB chunk partial
  // total 69,861,376 bytes

  prep_kernel<<<2816, 256, 0, stream>>>(x, W0, W1, W2, xb, Wt);
  gemm3<<<dim3(128, 4, 3), 256, 0, stream>>>(xb, Wt, b0, b1, b2, uP, e1P, e2P);
  rowsum<<<4096, 256, 0, stream>>>(e1P, e2P, iS1, iS2);
  scan_pass1<<<512, 256, 0, stream>>>(e1P, e2P, uP, iS1, iS2, cP, cS);
  scan_pass3<<<512, 256, 0, stream>>>(e1P, e2P, uP, iS1, iS2, cP, cS, out);
}

// Round 8
// 83.110 us; speedup vs baseline: 1.4871x; 1.0231x over previous
//
#include <hip/hip_runtime.h>
#include <hip/hip_bf16.h>

#define B_N 32
#define T_N 512
#define D_N 512
#define H_N 512
#define M_N (B_N * T_N)   // 16384

typedef __attribute__((ext_vector_type(8))) short bf16x8;   // generic 16B
typedef __attribute__((ext_vector_type(4))) float f32x4;

__device__ __forceinline__ unsigned short f2bf(float f) {
  unsigned u = __float_as_uint(f);
  u += 0x7FFFu + ((u >> 16) & 1u);   // RTNE
  return (unsigned short)(u >> 16);
}
__device__ __forceinline__ float bf2f(unsigned short h) {
  return __uint_as_float(((unsigned)h) << 16);
}
__device__ __forceinline__ unsigned short f2h(float f) {
  _Float16 h = (_Float16)f;
  return *(unsigned short*)&h;
}
__device__ __forceinline__ float h2f(unsigned short u) {
  _Float16 h = *(_Float16*)&u;
  return (float)h;
}

#define GLOAD16(g, l) __builtin_amdgcn_global_load_lds( \
    (const __attribute__((address_space(1))) void*)(g), \
    (__attribute__((address_space(3))) void*)(l), 16, 0, 0)

// ---------------------------------------------------------------------------
// prep: blocks [0,768) transpose+convert W -> Wt[id][n][k] bf16;
// blocks [768, 2816) convert x f32 -> bf16.
// ---------------------------------------------------------------------------
__global__ void prep_kernel(const float* __restrict__ x,
                            const float* __restrict__ W0,
                            const float* __restrict__ W1,
                            const float* __restrict__ W2,
                            unsigned short* __restrict__ xb,
                            unsigned short* __restrict__ Wt) {
  int blk = blockIdx.x;
  int tid = threadIdx.x;
  if (blk < 768) {
    __shared__ float tile[32][33];
    int id = blk >> 8;
    int t = blk & 255;
    int kr = (t >> 4) << 5;
    int nc = (t & 15) << 5;
    const float* W = (id == 0) ? W0 : (id == 1) ? W1 : W2;
    unsigned short* Wo = Wt + (size_t)id * (D_N * H_N);
    int tx = tid & 31, ty0 = tid >> 5;
    for (int ty = ty0; ty < 32; ty += 8)
      tile[ty][tx] = W[(size_t)(kr + ty) * H_N + nc + tx];
    __syncthreads();
    for (int ty = ty0; ty < 32; ty += 8)
      Wo[(size_t)(nc + ty) * D_N + kr + tx] = f2bf(tile[tx][ty]);
  } else {
    int b = blk - 768;
    const float4* xv = (const float4*)x;
#pragma unroll
    for (int u = 0; u < 4; ++u) {
      int i = b * 1024 + u * 256 + tid;
      float4 v = xv[i];
      ushort4 o;
      o.x = f2bf(v.x); o.y = f2bf(v.y); o.z = f2bf(v.z); o.w = f2bf(v.w);
      ((ushort4*)xb)[i] = o;
    }
  }
}

// ---------------------------------------------------------------------------
// gemm3 v7: m97 geometry (128x128 tile, BK=64, 4 waves) + DOUBLE-BUFFERED
// LDS (2x32KB = 64KB -> same 2 blocks/CU as the measured single-buffer v6)
// + counted vmcnt (T4): each stage has a full K-step + issue-phase of
// latency cover; never drains to 0 mid-loop.  Rolled {buf0,buf1} loop
// bounds liveness (v5 lesson); NO launch_bounds cap (v4/v5 spill lesson).
// Per thread per stage: 8 GLOAD16 (4 A + 4 B), uniform across waves ->
// vmcnt(8) drains exactly the previous stage.
// Epilogue elementwise (softmax decoupled): id0 tanh via exp+rcp, id1/2 exp.
// Swizzle (v1-verified): 128B rows, 16B slot p = s ^ (row&7); inverse on
// the per-lane GLOBAL source, linear LDS dest (rule 21).
// ---------------------------------------------------------------------------
__global__ __launch_bounds__(256) void gemm3(
    const unsigned short* __restrict__ xb,
    const unsigned short* __restrict__ Wt,
    const float* __restrict__ bDu,
    const float* __restrict__ bDr1,
    const float* __restrict__ bDr2,
    unsigned short* __restrict__ uP,
    unsigned short* __restrict__ e1P,
    unsigned short* __restrict__ e2P) {
  // A0 @0, A1 @16384, B0 @32768, B1 @49152  (each 128x64 bf16 = 16KB)
  __shared__ __align__(16) char smem[65536];

  const int tid = threadIdx.x;      // 0..255
  const int lane = tid & 63;
  const int wv = tid >> 6;          // 0..3
  const int wr = wv >> 1;           // wave row (0..1)
  const int wc = wv & 1;            // wave col (0..1)
  const int g = lane >> 4;          // 0..3
  const int c16 = lane & 15;

  const int m0 = blockIdx.x * 128;
  const int n0 = blockIdx.y * 128;
  const int id = blockIdx.z;
  const unsigned short* Wp = Wt + (size_t)id * (D_N * H_N);

  f32x4 acc[4][4];
#pragma unroll
  for (int mt = 0; mt < 4; ++mt)
#pragma unroll
    for (int nt = 0; nt < 4; ++nt)
      acc[mt][nt] = (f32x4){0.f, 0.f, 0.f, 0.f};

  // staging: tile = 1024 chunks of 16B; thread handles chunks i*256+tid.
  // row = i*32 + (tid>>3); phys slot = tid&7; logical slot = phys ^ (row&7)
  const int rowoff = tid >> 3;                         // 0..31
  const int lsl = ((tid & 7) ^ ((tid >> 3) & 7)) * 8;  // elems
  const unsigned short* aSrc = xb + (size_t)(m0 + rowoff) * D_N + lsl;
  const unsigned short* bSrc = Wp + (size_t)(n0 + rowoff) * D_N + lsl;
  const int dstOff = wv * 1024;   // wave-uniform part of LDS dest

  // read-side swizzle: row&7 == c16&7 for all fragments of this lane
  const int h3 = c16 & 7;

#define STAGE(buf, kstep) do {                                           \
    const int k0_ = (kstep) * 64;                                        \
    _Pragma("unroll")                                                    \
    for (int i = 0; i < 4; ++i)                                          \
      GLOAD16(aSrc + (size_t)i * (32 * D_N) + k0_,                       \
              smem + (buf) * 16384 + dstOff + i * 4096);                 \
    _Pragma("unroll")                                                    \
    for (int i = 0; i < 4; ++i)                                          \
      GLOAD16(bSrc + (size_t)i * (32 * D_N) + k0_,                       \
              smem + 32768 + (buf) * 16384 + dstOff + i * 4096);         \
  } while (0)

#define COMPUTE(buf) do {                                                \
    _Pragma("unroll")                                                    \
    for (int kh = 0; kh < 2; ++kh) {                                     \
      const int soff = ((kh * 4 + g) ^ h3) << 4;                         \
      bf16x8 af[4], bb[4];                                               \
      _Pragma("unroll")                                                  \
      for (int mt = 0; mt < 4; ++mt)                                     \
        af[mt] = *(const bf16x8*)(smem + (buf) * 16384 +                 \
                                  (wr * 64 + mt * 16 + c16) * 128 + soff); \
      _Pragma("unroll")                                                  \
      for (int nt = 0; nt < 4; ++nt)                                     \
        bb[nt] = *(const bf16x8*)(smem + 32768 + (buf) * 16384 +         \
                                  (wc * 64 + nt * 16 + c16) * 128 + soff); \
      _Pragma("unroll")                                                  \
      for (int mt = 0; mt < 4; ++mt)                                     \
        _Pragma("unroll")                                                \
        for (int nt = 0; nt < 4; ++nt)                                   \
          acc[mt][nt] = __builtin_amdgcn_mfma_f32_16x16x32_bf16(         \
              af[mt], bb[nt], acc[mt][nt], 0, 0, 0);                     \
    }                                                                    \
  } while (0)

#define WAIT8 asm volatile("s_waitcnt vmcnt(8)" ::: "memory")

  STAGE(0, 0);
#pragma unroll 1
  for (int i = 0; i < 3; ++i) {
    STAGE(1, 2 * i + 1);
    WAIT8;
    __syncthreads();
    COMPUTE(0);
    __syncthreads();
    STAGE(0, 2 * i + 2);
    WAIT8;
    __syncthreads();
    COMPUTE(1);
    __syncthreads();
  }
  // k=6 in buf0; stage k=7 into buf1
  STAGE(1, 7);
  WAIT8;
  __syncthreads();
  COMPUTE(0);
  __syncthreads();
  asm volatile("s_waitcnt vmcnt(0)" ::: "memory");
  __syncthreads();
  COMPUTE(1);

  // ---- elementwise epilogue ----
  const float* bp = (id == 0) ? bDu : (id == 1) ? bDr1 : bDr2;
  unsigned short* outp = (id == 0) ? uP : (id == 1) ? e1P : e2P;
  float bias[4];
#pragma unroll
  for (int nt = 0; nt < 4; ++nt)
    bias[nt] = bp[n0 + wc * 64 + nt * 16 + c16];

#pragma unroll
  for (int mt = 0; mt < 4; ++mt)
#pragma unroll
    for (int i = 0; i < 4; ++i) {
      int row = m0 + wr * 64 + mt * 16 + g * 4 + i;
      unsigned short* op = outp + (size_t)row * H_N + n0 + wc * 64 + c16;
      if (id == 0) {
#pragma unroll
        for (int nt = 0; nt < 4; ++nt) {
          float z = acc[mt][nt][i] + bias[nt];
          // tanh(z) = 1 - 2/(e^{2z}+1); saturates correctly for |z| large
          float e = __expf(2.f * z);
          op[nt * 16] = f2h(1.f - 2.f * __builtin_amdgcn_rcpf(e + 1.f));
        }
      } else {
#pragma unroll
        for (int nt = 0; nt < 4; ++nt)
          op[nt * 16] = f2h(__expf(acc[mt][nt][i] + bias[nt]));
      }
    }
#undef STAGE
#undef COMPUTE
#undef WAIT8
}

// ---------------------------------------------------------------------------
// rowsum: one wave per (b,t) row; computes 1/sum(e1) and 1/sum(e2).
// ---------------------------------------------------------------------------
__global__ void rowsum(const unsigned short* __restrict__ e1P,
                       const unsigned short* __restrict__ e2P,
                       float* __restrict__ iS1,
                       float* __restrict__ iS2) {
  int row = blockIdx.x * 4 + (threadIdx.x >> 6);
  int lane = threadIdx.x & 63;
  const bf16x8 v1 = *(const bf16x8*)(e1P + (size_t)row * H_N + lane * 8);
  const bf16x8 v2 = *(const bf16x8*)(e2P + (size_t)row * H_N + lane * 8);
  float s1 = 0.f, s2 = 0.f;
#pragma unroll
  for (int i = 0; i < 8; ++i) {
    s1 += h2f((unsigned short)v1[i]);
    s2 += h2f((unsigned short)v2[i]);
  }
#pragma unroll
  for (int d = 1; d < 64; d <<= 1) {
    s1 += __shfl_xor(s1, d);
    s2 += __shfl_xor(s2, d);
  }
  if (lane == 0) {
    iS1[row] = 1.f / s1;
    iS2[row] = 1.f / s2;
  }
}

// ---------------------------------------------------------------------------
// Chunked linear-recurrence scan: s_t = r1_t*s + r2_t*u_t, with
// r_i = e_i * invS_i applied on the fly (invS is lane-uniform -> broadcast).
// ---------------------------------------------------------------------------
__global__ void scan_pass1(const unsigned short* __restrict__ e1P,
                           const unsigned short* __restrict__ e2P,
                           const unsigned short* __restrict__ uP,
                           const float* __restrict__ iS1,
                           const float* __restrict__ iS2,
                           float* __restrict__ cP,
                           float* __restrict__ cS) {
  int gt = blockIdx.x * 256 + threadIdx.x;  // 0..131071
  int chunk = gt >> 14;
  int r = gt & 16383;
  int b = r >> 9, h = r & 511;
  int row0 = b * T_N + chunk * 64;
  size_t idx = (size_t)row0 * H_N + h;
  float p = 1.f, s = 0.f;
#pragma unroll 4
  for (int j = 0; j < 64; ++j) {
    float a = iS1[row0 + j] * h2f(e1P[idx]);
    float cu = iS2[row0 + j] * h2f(e2P[idx]) * h2f(uP[idx]);
    s = fmaf(a, s, cu);
    p *= a;
    idx += H_N;
  }
  cP[gt] = p;
  cS[gt] = s;
}

__global__ void scan_pass3(const unsigned short* __restrict__ e1P,
                           const unsigned short* __restrict__ e2P,
                           const unsigned short* __restrict__ uP,
                           const float* __restrict__ iS1,
                           const float* __restrict__ iS2,
                           const float* __restrict__ cP,
                           const float* __restrict__ cS,
                           float* __restrict__ out) {
  int gt = blockIdx.x * 256 + threadIdx.x;
  int chunk = gt >> 14;
  int r = gt & 16383;
  int b = r >> 9, h = r & 511;
  float s = 0.f;
  for (int c2 = 0; c2 < chunk; ++c2)
    s = fmaf(cP[c2 * 16384 + r], s, cS[c2 * 16384 + r]);
  int row0 = b * T_N + chunk * 64;
  size_t idx = (size_t)row0 * H_N + h;
#pragma unroll 4
  for (int j = 0; j < 64; ++j) {
    float a = iS1[row0 + j] * h2f(e1P[idx]);
    float cu = iS2[row0 + j] * h2f(e2P[idx]) * h2f(uP[idx]);
    s = fmaf(a, s, cu);
    out[idx] = s;
    idx += H_N;
  }
}

extern "C" void kernel_launch(void* const* d_in, const int* in_sizes, int n_in,
                              void* d_out, int out_size, void* d_ws, size_t ws_size,
                              hipStream_t stream) {
  const float* x  = (const float*)d_in[0];
  const float* W0 = (const float*)d_in[1];
  const float* W1 = (const float*)d_in[2];
  const float* W2 = (const float*)d_in[3];
  const float* b0 = (const float*)d_in[4];
  const float* b1 = (const float*)d_in[5];
  const float* b2 = (const float*)d_in[6];
  float* out = (float*)d_out;

  char* ws = (char*)d_ws;
  unsigned short* xb  = (unsigned short*)ws;                  // 16 MB  bf16 x
  unsigned short* Wt  = (unsigned short*)(ws + 16777216);     // 1.5 MB bf16 W^T x3
  unsigned short* uP  = (unsigned short*)(ws + 18350080);     // 16 MB  f16 tanh(u)
  unsigned short* e1P = (unsigned short*)(ws + 35127296);     // 16 MB  f16 exp(z1)
  unsigned short* e2P = (unsigned short*)(ws + 51904512);     // 16 MB  f16 exp(z2)
  float*          iS1 = (float*)(ws + 68681728);              // 64 KB  1/rowsum
  float*          iS2 = (float*)(ws + 68747264);              // 64 KB
  float*          cP  = (float*)(ws + 68812800);              // 0.5 MB chunk prod
  float*          cS  = (float*)(ws + 69337088);              // 0.5 MB chunk partial
  // total 69,861,376 bytes

  prep_kernel<<<2816, 256, 0, stream>>>(x, W0, W1, W2, xb, Wt);
  gemm3<<<dim3(128, 4, 3), 256, 0, stream>>>(xb, Wt, b0, b1, b2, uP, e1P, e2P);
  rowsum<<<4096, 256, 0, stream>>>(e1P, e2P, iS1, iS2);
  scan_pass1<<<512, 256, 0, stream>>>(e1P, e2P, uP, iS1, iS2, cP, cS);
  scan_pass3<<<512, 256, 0, stream>>>(e1P, e2P, uP, iS1, iS2, cP, cS, out);
}